// Round 15
// baseline (284.486 us; speedup 1.0000x reference)
//
#include <hip/hip_runtime.h>
#include <hip/hip_bf16.h>
#include <stdint.h>

#define BN 8192
#define DK 1024
#define BKT 64                // K elements (= bytes) per tile
#define NKT (DK / BKT)        // 16 K-tiles
#define LSMOOTH 0.1f
#define EPSF 1e-7f
#define LN2F 0.69314718055994531f

typedef float f32x4 __attribute__((ext_vector_type(4)));

// ---------------- prep: f32 -> e4m3 (x16 pre-scale) + row squared norms ----------------
__global__ __launch_bounds__(256) void prep_kernel(
    const float* __restrict__ sign, const float* __restrict__ text,
    uint32_t* __restrict__ Afp, uint32_t* __restrict__ Bfp,
    float* __restrict__ xx, float* __restrict__ yy) {
  const int b = blockIdx.x;          // 0..2*BN-1
  const int row = b & (BN - 1);
  const bool isB = b >= BN;
  const float4* src = (const float4*)((isB ? text : sign) + (size_t)row * DK);
  uint32_t* dst = (isB ? Bfp : Afp) + (size_t)row * (DK / 4);
  const int t = threadIdx.x;         // 256 threads, 1 float4 each
  float4 v = src[t];
  uint32_t u = 0;
  u = __builtin_amdgcn_cvt_pk_fp8_f32(v.x * 16.f, v.y * 16.f, u, false);  // HW RNE e4m3
  u = __builtin_amdgcn_cvt_pk_fp8_f32(v.z * 16.f, v.w * 16.f, u, true);
  dst[t] = u;
  float ss = v.x * v.x + v.y * v.y + v.z * v.z + v.w * v.w;  // norms stay exact f32
  #pragma unroll
  for (int off = 32; off; off >>= 1) ss += __shfl_down(ss, off);
  __shared__ float red[4];
  if ((t & 63) == 0) red[t >> 6] = ss;
  __syncthreads();
  if (t == 0) (isB ? yy : xx)[row] = red[0] + red[1] + red[2] + red[3];
}

// ---------------- fused GEMM: fp8, 128x128 tile, BK=64, 2 buffers, 4 blocks/CU --------
// 4 waves (2M x 2N), per-wave 64x64 -> acc[4][4] f32x4 = 64 regs; total budget <=128
// (launch_bounds(256,4)) -> 4 waves/SIMD = 4 co-resident blocks/CU (LDS 32KB x4=128KB).
// Cross-block TLP (m114) hides barrier/drain stalls that capped every 1-block/CU round.
// Loop: { STAGE(t+1 -> other buf); 16 ds_read_b64; 32 MFMA; vmcnt(0); barrier } — one
// barrier per K-tile, provably race-free. Addressing/swizzle identical to R14 (verified).
__global__ __launch_bounds__(256, 4) void gemm_fused(
    const uint8_t* __restrict__ Afp, const uint8_t* __restrict__ Bfp,
    const float* __restrict__ xx, const float* __restrict__ yy,
    const float* __restrict__ p_log_tau, const float* __restrict__ p_margin,
    float* __restrict__ row_partial, float* __restrict__ accums) {
  __shared__ __align__(16) char lds[32768];   // 2 buffers x (A 8KB + B 8KB)

  const int tid = threadIdx.x;
  const int wave = tid >> 6, lane = tid & 63;
  const int l15 = lane & 15, g4 = lane >> 4;
  const int waveM = wave >> 1, waveN = wave & 1;        // 2 x 2
  const int bx = blockIdx.x, by = blockIdx.y;
  const int blockRow = by * 128, blockCol = bx * 128;

  // staging: per GLL 256 threads cover 64 rows x 64B; thread t -> row t>>2,
  // 16B-chunk (t&3) ^ ((row>>1)&3) (pre-swizzled source; LDS written linearly by HW)
  const int srow = tid >> 2;                            // 0..63
  const int schunk = (tid & 3) ^ ((srow >> 1) & 3);     // involution
  const uint8_t* aSrc = Afp + (size_t)(blockRow + srow) * DK + schunk * 16;
  const uint8_t* bSrc = Bfp + (size_t)(blockCol + srow) * DK + schunk * 16;
  const int ldst = wave * 1024;                         // wave-uniform base in 4KB call

#define GLL(gp, lp) __builtin_amdgcn_global_load_lds(                                   \
      (const __attribute__((address_space(1))) void*)(gp),                             \
      (__attribute__((address_space(3))) void*)(lp), 16, 0, 0)
#define STAGE_AB(kt, cb) do {                                                           \
    const uint8_t* sa_ = aSrc + (kt) * BKT;                                             \
    const uint8_t* sb_ = bSrc + (kt) * BKT;                                             \
    GLL(sa_,           lds + (cb) + ldst);                                              \
    GLL(sa_ + 64 * DK, lds + (cb) + 4096 + ldst);                                       \
    GLL(sb_,           lds + (cb) + 8192 + ldst);                                       \
    GLL(sb_ + 64 * DK, lds + (cb) + 12288 + ldst); } while (0)
#define RD64(off) (*(const long*)(lds + (off)))
#define MFMA8(a_, b_, c_) __builtin_amdgcn_mfma_f32_16x16x32_fp8_fp8((a_), (b_), (c_), 0, 0, 0)

  f32x4 acc[4][4];
  #pragma unroll
  for (int m = 0; m < 4; ++m)
    #pragma unroll
    for (int n = 0; n < 4; ++n)
      acc[m][n] = (f32x4){0.f, 0.f, 0.f, 0.f};

  // frag reads: 64B rows; lane reads 8B at K-offset kk*32 + g4*8, chunk XOR (row>>1)&3.
  const int s2 = (l15 >> 1) & 3;
  const int co0 = (((g4 >> 1) ^ s2) << 4) + ((g4 & 1) << 3);          // kk=0
  const int co1 = ((((g4 >> 1) + 2) ^ s2) << 4) + ((g4 & 1) << 3);    // kk=1
  const int aRow = (waveM * 64 + l15) * 64;             // + m*1024
  const int bRow = 8192 + (waveN * 64 + l15) * 64;      // + n*1024

  // prologue: stage tile 0 into buffer 0, drain, barrier
  STAGE_AB(0, 0);
  asm volatile("s_waitcnt vmcnt(0)" ::: "memory");
  __builtin_amdgcn_s_barrier();
  asm volatile("" ::: "memory");

  for (int t = 0; t < NKT; ++t) {
    const int cb = (t & 1) * 16384;
    if (t + 1 < NKT) STAGE_AB(t + 1, 16384 - cb);       // other buffer
    long af[4][2];
    #pragma unroll
    for (int m = 0; m < 4; ++m) {
      af[m][0] = RD64(cb + aRow + m * 1024 + co0);
      af[m][1] = RD64(cb + aRow + m * 1024 + co1);
    }
    __builtin_amdgcn_s_setprio(1);
    #pragma unroll
    for (int n = 0; n < 4; ++n) {
      const long bf0 = RD64(cb + bRow + n * 1024 + co0);
      const long bf1 = RD64(cb + bRow + n * 1024 + co1);
      #pragma unroll
      for (int m = 0; m < 4; ++m) {
        acc[m][n] = MFMA8(af[m][0], bf0, acc[m][n]);
        acc[m][n] = MFMA8(af[m][1], bf1, acc[m][n]);
      }
    }
    __builtin_amdgcn_s_setprio(0);
    // drain this iter's 4 GLLs (issued before ~1500 cyc of reads+MFMA); barrier frees
    // buffer cb for overwrite next iter and publishes buffer cb^1 for next reads
    asm volatile("s_waitcnt vmcnt(0)" ::: "memory");
    __builtin_amdgcn_s_barrier();
    asm volatile("" ::: "memory");
  }
#undef STAGE_AB
#undef GLL
#undef RD64
#undef MFMA8

  // ---- fused epilogue: poincare dist via log2, exp-sums, dist sums ----
  const float lt = *p_log_tau;
  const float mg = *p_margin;
  const float marg = fmaxf(mg, 0.f);
  const float tau = 1.99f / (1.f + __expf(-lt)) + 0.01f;
  const float nl = -LN2F / tau;            // exp(L2*nl) == exp(-dist/tau)
  const float em = __expf(-marg);          // diagonal exp correction factor
  const bool diagblk = (bx == by);
  const float inv256 = 0.00390625f;        // undo x16 * x16 input scaling (exact)

  float yyj[4], rcpy[4]; int gj[4];
  #pragma unroll
  for (int n = 0; n < 4; ++n) {
    gj[n] = blockCol + waveN * 64 + n * 16 + l15;        // C/D col = lane&15
    yyj[n] = yy[gj[n]];
    rcpy[n] = __builtin_amdgcn_rcpf(1.f - yyj[n]);
  }

  float dL = 0.f, dDiagL = 0.f;            // dist sums in log2 units
  float* rsum = (float*)lds;               // reuse LDS: [128 rows][2 waveN] partials

  #pragma unroll
  for (int m = 0; m < 4; ++m) {
    #pragma unroll
    for (int r = 0; r < 4; ++r) {
      const int rloc = waveM * 64 + m * 16 + g4 * 4 + r;
      const int gi = blockRow + rloc;                    // C/D row
      const float xxi = xx[gi];
      const float p2 = 2.f * __builtin_amdgcn_rcpf(1.f - xxi);
      float e_acc = 0.f;
      #pragma unroll
      for (int n = 0; n < 4; ++n) {
        const float xy = acc[m][n][r] * inv256;
        const float sq = fmaxf(xxi + yyj[n] - 2.f * xy, 0.f);
        const float tt = sq * (p2 * rcpy[n]);            // arg = 1 + tt
        const float s = __builtin_amdgcn_sqrtf(tt * (tt + 2.f));
        const float w = tt + 1.f + s;                    // arg + sqrt(arg^2-1)
        const float L2 = __log2f(fmaxf(w, 1.f + EPSF));  // dist = L2 * ln2
        float e = __expf(L2 * nl);
        dL += L2;
        if (diagblk && gi == gj[n]) { dDiagL += L2; e *= em; }
        e_acc += e;
      }
      e_acc += __shfl_xor(e_acc, 1);
      e_acc += __shfl_xor(e_acc, 2);
      e_acc += __shfl_xor(e_acc, 4);
      e_acc += __shfl_xor(e_acc, 8);
      if (l15 == 0) rsum[rloc * 2 + waveN] = e_acc;
    }
  }

  // block-level scalar reductions -> 2 atomics per wave (log2 units)
  #pragma unroll
  for (int off = 32; off; off >>= 1) {
    dL += __shfl_down(dL, off);
    dDiagL += __shfl_down(dDiagL, off);
  }
  if (lane == 0) {
    atomicAdd(&accums[0], dL);
    if (diagblk) atomicAdd(&accums[1], dDiagL);
  }

  __syncthreads();
  if (tid < 128) {
    const float rs = rsum[tid * 2 + 0] + rsum[tid * 2 + 1];
    row_partial[(size_t)bx * BN + blockRow + tid] = rs;
  }
}

// ---------------- logsum: per-row sum of 64 col-tile partials, log, block-reduce ------
__global__ __launch_bounds__(256) void logsum_kernel(
    const float* __restrict__ row_partial, float* __restrict__ accums) {
  const int row = blockIdx.x * 256 + threadIdx.x;       // 32 blocks x 256 = 8192 rows
  float s = 0.f;
  #pragma unroll
  for (int c = 0; c < 64; ++c) s += row_partial[(size_t)c * BN + row];
  float lsum = __logf(s);
  #pragma unroll
  for (int off = 32; off; off >>= 1) lsum += __shfl_down(lsum, off);
  __shared__ float red[4];
  if ((threadIdx.x & 63) == 0) red[threadIdx.x >> 6] = lsum;
  __syncthreads();
  if (threadIdx.x == 0)
    atomicAdd(&accums[2], red[0] + red[1] + red[2] + red[3]);
}

// ---------------- final: linear combination ----------------
__global__ void final_kernel(
    const float* __restrict__ accums,
    const float* __restrict__ p_log_tau, const float* __restrict__ p_margin,
    float* __restrict__ out) {
  const float lt = *p_log_tau;
  const float mg = *p_margin;
  const float marg = fmaxf(mg, 0.f);
  const float tau = 1.99f / (1.f + __expf(-lt)) + 0.01f;
  const float C = marg;
  const float d_tot = accums[0] * LN2F;
  const float d_diag = accums[1] * LN2F;
  const float bf = (float)BN;
  const float mean_lse = accums[2] / bf + C;
  const float sum_scores = -d_tot / tau + marg * (bf * bf - bf);  // margin closed-form
  const float sum_diag_scores = -d_diag / tau;
  const float loss = mean_lse
                   - (1.f - LSMOOTH) * (sum_diag_scores / bf)
                   - LSMOOTH * (sum_scores / (bf * bf));
  out[0] = loss;
  out[1] = d_diag / bf;   // pos_dist
  out[2] = tau;
  out[3] = mg;            // maximum(margin, margin) == margin
}

extern "C" void kernel_launch(void* const* d_in, const int* in_sizes, int n_in,
                              void* d_out, int out_size, void* d_ws, size_t ws_size,
                              hipStream_t stream) {
  const float* sign = (const float*)d_in[0];
  const float* text = (const float*)d_in[1];
  const float* p_log_tau = (const float*)d_in[2];
  const float* p_margin = (const float*)d_in[3];
  float* out = (float*)d_out;

  char* ws = (char*)d_ws;
  uint8_t* Afp = (uint8_t*)ws;                                       // 8 MiB
  uint8_t* Bfp = (uint8_t*)(ws + (size_t)BN * DK);                   // 8 MiB
  float* xx = (float*)(ws + (size_t)BN * DK * 2);
  float* yy = xx + BN;
  float* row_partial = yy + BN;                                      // 64 x 8192 floats
  float* accums = row_partial + 64 * BN;                             // 3 floats

  (void)hipMemsetAsync(accums, 0, 3 * sizeof(float), stream);
  prep_kernel<<<dim3(2 * BN), 256, 0, stream>>>(sign, text, (uint32_t*)Afp, (uint32_t*)Bfp, xx, yy);
  gemm_fused<<<dim3(BN / 128, BN / 128), 256, 0, stream>>>(
      Afp, Bfp, xx, yy, p_log_tau, p_margin, row_partial, accums);
  logsum_kernel<<<dim3(BN / 256), 256, 0, stream>>>(row_partial, accums);
  final_kernel<<<1, 1, 0, stream>>>(accums, p_log_tau, p_margin, out);
}

// Round 16
// 244.149 us; speedup vs baseline: 1.1652x; 1.1652x over previous
//
#include <hip/hip_runtime.h>
#include <hip/hip_bf16.h>
#include <stdint.h>

#define BN 8192
#define DK 1024
#define BKT 64                // K elements (= bytes) per tile
#define NKT (DK / BKT)        // 16 K-tiles
#define LSMOOTH 0.1f
#define EPSF 1e-7f
#define LN2F 0.69314718055994531f

typedef float f32x4 __attribute__((ext_vector_type(4)));

// ---------------- prep: f32 -> e4m3 (x16 pre-scale) + row squared norms ----------------
__global__ __launch_bounds__(256) void prep_kernel(
    const float* __restrict__ sign, const float* __restrict__ text,
    uint32_t* __restrict__ Afp, uint32_t* __restrict__ Bfp,
    float* __restrict__ xx, float* __restrict__ yy) {
  const int b = blockIdx.x;          // 0..2*BN-1
  const int row = b & (BN - 1);
  const bool isB = b >= BN;
  const float4* src = (const float4*)((isB ? text : sign) + (size_t)row * DK);
  uint32_t* dst = (isB ? Bfp : Afp) + (size_t)row * (DK / 4);
  const int t = threadIdx.x;         // 256 threads, 1 float4 each
  float4 v = src[t];
  uint32_t u = 0;
  u = __builtin_amdgcn_cvt_pk_fp8_f32(v.x * 16.f, v.y * 16.f, u, false);  // HW RNE e4m3
  u = __builtin_amdgcn_cvt_pk_fp8_f32(v.z * 16.f, v.w * 16.f, u, true);
  dst[t] = u;
  float ss = v.x * v.x + v.y * v.y + v.z * v.z + v.w * v.w;  // norms stay exact f32
  #pragma unroll
  for (int off = 32; off; off >>= 1) ss += __shfl_down(ss, off);
  __shared__ float red[4];
  if ((t & 63) == 0) red[t >> 6] = ss;
  __syncthreads();
  if (t == 0) (isB ? yy : xx)[row] = red[0] + red[1] + red[2] + red[3];
}

// ---------------- fused GEMM: fp8, 256x256, BK=64, 3-slot ring, fine phases + counted
// vmcnt (T3+T4 combined — the cell m218 isolates as +38-73%). 8 waves (2M x 4N),
// per-wave 128x64. Phases per tile: {12 reads + stageA(t+2)}, {4 reads + stageB(t+2)},
// {8 reads}, {0 reads + vmcnt(4)}. End-of-tile vmcnt(4) keeps t+2's 4 GLLs in flight
// across 8 barriers; only t+1's (a full tile old) must land. NEVER drains to 0 mid-loop.
// Ring race-free: slot (t+2)%3 last read in tile t-1, all reads drained by in-phase
// lgkmcnt(0) before that tile's closing barrier. Swizzle/addressing = R14 (verified).
__global__ __launch_bounds__(512, 2) void gemm_fused(
    const uint8_t* __restrict__ Afp, const uint8_t* __restrict__ Bfp,
    const float* __restrict__ xx, const float* __restrict__ yy,
    const float* __restrict__ p_log_tau, const float* __restrict__ p_margin,
    float* __restrict__ row_partial, float* __restrict__ accums) {
  __shared__ __align__(16) char lds[98304];   // 3 slots x (A 16KB + B 16KB)

  const int tid = threadIdx.x;
  const int wave = tid >> 6, lane = tid & 63;
  const int l15 = lane & 15, g4 = lane >> 4;
  const int waveM = wave >> 2, waveN = wave & 3;        // 2 x 4
  const int bx = blockIdx.x, by = blockIdx.y;
  const int blockRow = by * 256, blockCol = bx * 256;

  // staging: per GLL 512 threads cover 128 rows x 64B; thread t -> row t>>2,
  // 16B-chunk (t&3) ^ ((row>>1)&3) (pre-swizzled source; LDS written linearly by HW)
  const int srow = tid >> 2;                            // 0..127
  const int schunk = (tid & 3) ^ ((srow >> 1) & 3);     // involution
  const uint8_t* aSrc = Afp + (size_t)(blockRow + srow) * DK + schunk * 16;
  const uint8_t* bSrc = Bfp + (size_t)(blockCol + srow) * DK + schunk * 16;
  const int ldst = wave * 1024;                         // wave-uniform base in 8KB call

#define GLL(gp, lp) __builtin_amdgcn_global_load_lds(                                   \
      (const __attribute__((address_space(1))) void*)(gp),                             \
      (__attribute__((address_space(3))) void*)(lp), 16, 0, 0)
#define STAGE_A(kt, cb) do { char* b_ = lds + (cb);                                     \
    const uint8_t* s_ = aSrc + (kt) * BKT;                                              \
    GLL(s_, b_ + ldst); GLL(s_ + 128 * DK, b_ + 8192 + ldst); } while (0)
#define STAGE_B(kt, cb) do { char* b_ = lds + (cb) + 16384;                             \
    const uint8_t* s_ = bSrc + (kt) * BKT;                                              \
    GLL(s_, b_ + ldst); GLL(s_ + 128 * DK, b_ + 8192 + ldst); } while (0)
#define RD64(off) (*(const long*)(lds + (off)))
#define BAR() do { __builtin_amdgcn_s_barrier(); asm volatile("" ::: "memory"); } while (0)
#define LGKM0() do { asm volatile("s_waitcnt lgkmcnt(0)" ::: "memory");                 \
                     __builtin_amdgcn_sched_barrier(0); } while (0)
#define MFMA8(a_, b_, c_) __builtin_amdgcn_mfma_f32_16x16x32_fp8_fp8((a_), (b_), (c_), 0, 0, 0)

  f32x4 acc[8][4];
  #pragma unroll
  for (int m = 0; m < 8; ++m)
    #pragma unroll
    for (int n = 0; n < 4; ++n)
      acc[m][n] = (f32x4){0.f, 0.f, 0.f, 0.f};

  // frag reads: 64B rows; lane reads 8B at K-offset kk*32 + g4*8, chunk XOR (row>>1)&3.
  const int s2 = (l15 >> 1) & 3;
  const int co0 = (((g4 >> 1) ^ s2) << 4) + ((g4 & 1) << 3);          // kk=0
  const int co1 = ((((g4 >> 1) + 2) ^ s2) << 4) + ((g4 & 1) << 3);    // kk=1
  const int aRow = (waveM * 128 + l15) * 64;            // + m*1024
  const int bRow = 16384 + (waveN * 64 + l15) * 64;     // + n*1024

  long af[4][2], bf[4][2];

  // prologue: stage tiles 0 (slot0) and 1 (slot1); drain tile 0's 4, keep tile 1's 4
  STAGE_A(0, 0); STAGE_B(0, 0); STAGE_A(1, 32768); STAGE_B(1, 32768);
  asm volatile("s_waitcnt vmcnt(4)" ::: "memory");
  BAR();

  int cs = 0;                                           // slot byte-base of tile t
  int ns = 65536;                                       // slot byte-base of tile t+2
  for (int t = 0; t < NKT; ++t) {
    const int cb = cs;
    // ---- phase 0: Q(m0-3 x n0-1); 12 reads; stage A(t+2) ----
    #pragma unroll
    for (int m = 0; m < 4; ++m) {
      af[m][0] = RD64(cb + aRow + m * 1024 + co0);
      af[m][1] = RD64(cb + aRow + m * 1024 + co1);
    }
    #pragma unroll
    for (int n = 0; n < 2; ++n) {
      bf[n][0] = RD64(cb + bRow + n * 1024 + co0);
      bf[n][1] = RD64(cb + bRow + n * 1024 + co1);
    }
    if (t + 2 < NKT) STAGE_A(t + 2, ns);
    BAR(); LGKM0();
    __builtin_amdgcn_s_setprio(1);
    #pragma unroll
    for (int m = 0; m < 4; ++m)
      #pragma unroll
      for (int n = 0; n < 2; ++n) {
        acc[m][n] = MFMA8(af[m][0], bf[n][0], acc[m][n]);
        acc[m][n] = MFMA8(af[m][1], bf[n][1], acc[m][n]);
      }
    __builtin_amdgcn_s_setprio(0);
    BAR();
    // ---- phase 1: Q(m0-3 x n2-3); 4 reads; stage B(t+2) ----
    #pragma unroll
    for (int n = 2; n < 4; ++n) {
      bf[n][0] = RD64(cb + bRow + n * 1024 + co0);
      bf[n][1] = RD64(cb + bRow + n * 1024 + co1);
    }
    if (t + 2 < NKT) STAGE_B(t + 2, ns);
    BAR(); LGKM0();
    __builtin_amdgcn_s_setprio(1);
    #pragma unroll
    for (int m = 0; m < 4; ++m)
      #pragma unroll
      for (int n = 2; n < 4; ++n) {
        acc[m][n] = MFMA8(af[m][0], bf[n][0], acc[m][n]);
        acc[m][n] = MFMA8(af[m][1], bf[n][1], acc[m][n]);
      }
    __builtin_amdgcn_s_setprio(0);
    BAR();
    // ---- phase 2: Q(m4-7 x n0-1); 8 reads (overwrite af) ----
    #pragma unroll
    for (int m = 0; m < 4; ++m) {
      af[m][0] = RD64(cb + aRow + (m + 4) * 1024 + co0);
      af[m][1] = RD64(cb + aRow + (m + 4) * 1024 + co1);
    }
    BAR(); LGKM0();
    __builtin_amdgcn_s_setprio(1);
    #pragma unroll
    for (int m = 0; m < 4; ++m)
      #pragma unroll
      for (int n = 0; n < 2; ++n) {
        acc[m + 4][n] = MFMA8(af[m][0], bf[n][0], acc[m + 4][n]);
        acc[m + 4][n] = MFMA8(af[m][1], bf[n][1], acc[m + 4][n]);
      }
    __builtin_amdgcn_s_setprio(0);
    BAR();
    // ---- phase 3: Q(m4-7 x n2-3); no reads; COUNTED vmcnt at tile end ----
    __builtin_amdgcn_s_setprio(1);
    #pragma unroll
    for (int m = 0; m < 4; ++m)
      #pragma unroll
      for (int n = 2; n < 4; ++n) {
        acc[m + 4][n] = MFMA8(af[m][0], bf[n][0], acc[m + 4][n]);
        acc[m + 4][n] = MFMA8(af[m][1], bf[n][1], acc[m + 4][n]);
      }
    __builtin_amdgcn_s_setprio(0);
    // t+2's 4 GLLs (issued this tile) stay in flight; t+1's (a full tile old) land.
    if (t + 3 <= NKT) asm volatile("s_waitcnt vmcnt(4)" ::: "memory");
    else              asm volatile("s_waitcnt vmcnt(0)" ::: "memory");
    BAR();
    cs = (cs == 65536) ? 0 : cs + 32768;
    ns = (ns == 65536) ? 0 : ns + 32768;
  }
#undef STAGE_A
#undef STAGE_B
#undef GLL
#undef RD64
#undef BAR
#undef LGKM0
#undef MFMA8

  // ---- fused epilogue: poincare dist via log2, exp-sums, dist sums ----
  const float lt = *p_log_tau;
  const float mg = *p_margin;
  const float marg = fmaxf(mg, 0.f);
  const float tau = 1.99f / (1.f + __expf(-lt)) + 0.01f;
  const float nl = -LN2F / tau;            // exp(L2*nl) == exp(-dist/tau)
  const float em = __expf(-marg);          // diagonal exp correction factor
  const bool diagblk = (bx == by);
  const float inv256 = 0.00390625f;        // undo x16 * x16 input scaling (exact)

  float yyj[4], rcpy[4]; int gj[4];
  #pragma unroll
  for (int n = 0; n < 4; ++n) {
    gj[n] = blockCol + waveN * 64 + n * 16 + l15;        // C/D col = lane&15
    yyj[n] = yy[gj[n]];
    rcpy[n] = __builtin_amdgcn_rcpf(1.f - yyj[n]);
  }

  float dL = 0.f, dDiagL = 0.f;            // dist sums in log2 units
  float* rsum = (float*)lds;               // reuse LDS: [256 rows][4 waveN] partials

  #pragma unroll
  for (int m = 0; m < 8; ++m) {
    #pragma unroll
    for (int r = 0; r < 4; ++r) {
      const int gi = blockRow + waveM * 128 + m * 16 + g4 * 4 + r;  // C/D row
      const float xxi = xx[gi];
      const float p2 = 2.f * __builtin_amdgcn_rcpf(1.f - xxi);
      float e_acc = 0.f;
      #pragma unroll
      for (int n = 0; n < 4; ++n) {
        const float xy = acc[m][n][r] * inv256;
        const float sq = fmaxf(xxi + yyj[n] - 2.f * xy, 0.f);
        const float tt = sq * (p2 * rcpy[n]);            // arg = 1 + tt
        const float s = __builtin_amdgcn_sqrtf(tt * (tt + 2.f));
        const float w = tt + 1.f + s;                    // arg + sqrt(arg^2-1)
        const float L2 = __log2f(fmaxf(w, 1.f + EPSF));  // dist = L2 * ln2
        float e = __expf(L2 * nl);
        dL += L2;
        if (diagblk && gi == gj[n]) { dDiagL += L2; e *= em; }
        e_acc += e;
      }
      e_acc += __shfl_xor(e_acc, 1);
      e_acc += __shfl_xor(e_acc, 2);
      e_acc += __shfl_xor(e_acc, 4);
      e_acc += __shfl_xor(e_acc, 8);
      if (l15 == 0) {
        const int rloc = waveM * 128 + m * 16 + g4 * 4 + r;
        rsum[rloc * 4 + waveN] = e_acc;
      }
    }
  }

  // block-level scalar reductions -> 2 atomics per wave (log2 units)
  #pragma unroll
  for (int off = 32; off; off >>= 1) {
    dL += __shfl_down(dL, off);
    dDiagL += __shfl_down(dDiagL, off);
  }
  if (lane == 0) {
    atomicAdd(&accums[0], dL);
    if (diagblk) atomicAdd(&accums[1], dDiagL);
  }

  __syncthreads();
  if (tid < 256) {
    const float rs = rsum[tid * 4 + 0] + rsum[tid * 4 + 1] + rsum[tid * 4 + 2] + rsum[tid * 4 + 3];
    row_partial[(size_t)bx * BN + blockRow + tid] = rs;
  }
}

// ---------------- finalize: sum col-tile partials, log, final linear combo ----------------
__global__ __launch_bounds__(1024) void finalize_kernel(
    const float* __restrict__ row_partial, const float* __restrict__ accums,
    const float* __restrict__ p_log_tau, const float* __restrict__ p_margin,
    float* __restrict__ out) {
  const int t = threadIdx.x;
  float lsum = 0.f;
  for (int i = t; i < BN; i += 1024) {
    float s = 0.f;
    #pragma unroll
    for (int c = 0; c < 32; ++c) s += row_partial[(size_t)c * BN + i];
    lsum += __logf(s);
  }
  #pragma unroll
  for (int off = 32; off; off >>= 1) lsum += __shfl_down(lsum, off);
  __shared__ float red[16];
  if ((t & 63) == 0) red[t >> 6] = lsum;
  __syncthreads();
  if (t == 0) {
    float total = 0.f;
    #pragma unroll
    for (int w = 0; w < 16; ++w) total += red[w];
    const float lt = *p_log_tau;
    const float mg = *p_margin;
    const float marg = fmaxf(mg, 0.f);
    const float tau = 1.99f / (1.f + __expf(-lt)) + 0.01f;
    const float C = marg;
    const float d_tot = accums[0] * LN2F;
    const float d_diag = accums[1] * LN2F;
    const float bf = (float)BN;
    const float mean_lse = total / bf + C;
    const float sum_scores = -d_tot / tau + marg * (bf * bf - bf);  // margin closed-form
    const float sum_diag_scores = -d_diag / tau;
    const float loss = mean_lse
                     - (1.f - LSMOOTH) * (sum_diag_scores / bf)
                     - LSMOOTH * (sum_scores / (bf * bf));
    out[0] = loss;
    out[1] = d_diag / bf;   // pos_dist
    out[2] = tau;
    out[3] = mg;            // maximum(margin, margin) == margin
  }
}

extern "C" void kernel_launch(void* const* d_in, const int* in_sizes, int n_in,
                              void* d_out, int out_size, void* d_ws, size_t ws_size,
                              hipStream_t stream) {
  const float* sign = (const float*)d_in[0];
  const float* text = (const float*)d_in[1];
  const float* p_log_tau = (const float*)d_in[2];
  const float* p_margin = (const float*)d_in[3];
  float* out = (float*)d_out;

  char* ws = (char*)d_ws;
  uint8_t* Afp = (uint8_t*)ws;                                       // 8 MiB
  uint8_t* Bfp = (uint8_t*)(ws + (size_t)BN * DK);                   // 8 MiB
  float* xx = (float*)(ws + (size_t)BN * DK * 2);
  float* yy = xx + BN;
  float* row_partial = yy + BN;                                      // 32 x 8192 floats
  float* accums = row_partial + 32 * BN;                             // 2 floats

  (void)hipMemsetAsync(accums, 0, 2 * sizeof(float), stream);
  prep_kernel<<<dim3(2 * BN), 256, 0, stream>>>(sign, text, (uint32_t*)Afp, (uint32_t*)Bfp, xx, yy);
  gemm_fused<<<dim3(BN / 256, BN / 256), 512, 0, stream>>>(
      Afp, Bfp, xx, yy, p_log_tau, p_margin, row_partial, accums);
  finalize_kernel<<<1, 1024, 0, stream>>>(row_partial, accums, p_log_tau, p_margin, out);
}

// Round 17
// 199.598 us; speedup vs baseline: 1.4253x; 1.2232x over previous
//
#include <hip/hip_runtime.h>
#include <hip/hip_bf16.h>
#include <stdint.h>

#define BN 8192
#define DK 1024
#define BKT 64                // K elements (= bytes) per tile
#define NKT (DK / BKT)        // 16 K-tiles
#define LSMOOTH 0.1f
#define EPSF 1e-7f
#define LN2F 0.69314718055994531f

typedef float f32x4 __attribute__((ext_vector_type(4)));
typedef int   i32x4 __attribute__((ext_vector_type(4)));

// ---------------- prep: f32 -> i8 (x1024, clamp +-127) + row norms + accums zero ------
__global__ __launch_bounds__(256) void prep_kernel(
    const float* __restrict__ sign, const float* __restrict__ text,
    uint32_t* __restrict__ Aq, uint32_t* __restrict__ Bq,
    float* __restrict__ xx, float* __restrict__ yy, float* __restrict__ accums) {
  const int b = blockIdx.x;          // 0..2*BN-1
  const int row = b & (BN - 1);
  const bool isB = b >= BN;
  const float4* src = (const float4*)((isB ? text : sign) + (size_t)row * DK);
  uint32_t* dst = (isB ? Bq : Aq) + (size_t)row * (DK / 4);
  const int t = threadIdx.x;         // 256 threads, 1 float4 each
  if (b == 0 && t < 2) accums[t] = 0.f;                 // fold memset into prep
  float4 v = src[t];
  int q0 = __float2int_rn(fminf(fmaxf(v.x * 1024.f, -127.f), 127.f));
  int q1 = __float2int_rn(fminf(fmaxf(v.y * 1024.f, -127.f), 127.f));
  int q2 = __float2int_rn(fminf(fmaxf(v.z * 1024.f, -127.f), 127.f));
  int q3 = __float2int_rn(fminf(fmaxf(v.w * 1024.f, -127.f), 127.f));
  dst[t] = (uint32_t)(q0 & 0xFF) | ((uint32_t)(q1 & 0xFF) << 8) |
           ((uint32_t)(q2 & 0xFF) << 16) | ((uint32_t)(q3 & 0xFF) << 24);
  float ss = v.x * v.x + v.y * v.y + v.z * v.z + v.w * v.w;  // norms exact f32
  #pragma unroll
  for (int off = 32; off; off >>= 1) ss += __shfl_down(ss, off);
  __shared__ float red[4];
  if ((t & 63) == 0) red[t >> 6] = ss;
  __syncthreads();
  if (t == 0) (isB ? yy : xx)[row] = red[0] + red[1] + red[2] + red[3];
}

// ---------------- fused GEMM: R14 structure, i8 dtype (16x16x64, K=64/inst) -----------
// 8 waves (2M x 4N), per-wave 128x64, mfma_i32_16x16x64_i8: i32x4 operands (one b128
// read each), i32x4 acc — exact integer dot products, dequant 2^-20 in epilogue.
// Per K64-tile: 32 MFMA in 4 phases of 8 (vs fp8's 64 in 4 of 16) — MFMA cluster
// halves inside the serial phase path. Staging/swizzle/sync byte-identical to R14.
__global__ __launch_bounds__(512, 2) void gemm_fused(
    const uint8_t* __restrict__ Aq, const uint8_t* __restrict__ Bq,
    const float* __restrict__ xx, const float* __restrict__ yy,
    const float* __restrict__ p_log_tau, const float* __restrict__ p_margin,
    float* __restrict__ row_partial, float* __restrict__ accums) {
  __shared__ __align__(16) char lds[65536];   // 2 buffers x (A 16KB + B 16KB)

  const int tid = threadIdx.x;
  const int wave = tid >> 6, lane = tid & 63;
  const int l15 = lane & 15, g4 = lane >> 4;
  const int waveM = wave >> 2, waveN = wave & 3;        // 2 x 4
  const int bx = blockIdx.x, by = blockIdx.y;
  const int blockRow = by * 256, blockCol = bx * 256;

  // staging: per GLL 512 threads cover 128 rows x 64B; thread t -> row t>>2,
  // 16B-chunk (t&3) ^ ((row>>1)&3) (pre-swizzled source; LDS written linearly by HW)
  const int srow = tid >> 2;                            // 0..127
  const int schunk = (tid & 3) ^ ((srow >> 1) & 3);     // involution
  const uint8_t* aSrc = Aq + (size_t)(blockRow + srow) * DK + schunk * 16;
  const uint8_t* bSrc = Bq + (size_t)(blockCol + srow) * DK + schunk * 16;
  const int ldst = wave * 1024;                         // wave-uniform base in 8KB call

#define GLL(gp, lp) __builtin_amdgcn_global_load_lds(                                   \
      (const __attribute__((address_space(1))) void*)(gp),                             \
      (__attribute__((address_space(3))) void*)(lp), 16, 0, 0)
#define STAGE_A(kt, cb) do { char* b_ = lds + (cb);                                     \
    const uint8_t* s_ = aSrc + (kt) * BKT;                                              \
    GLL(s_, b_ + ldst); GLL(s_ + 128 * DK, b_ + 8192 + ldst); } while (0)
#define STAGE_B(kt, cb) do { char* b_ = lds + (cb) + 16384;                             \
    const uint8_t* s_ = bSrc + (kt) * BKT;                                              \
    GLL(s_, b_ + ldst); GLL(s_ + 128 * DK, b_ + 8192 + ldst); } while (0)
#define RD128(off) (*(const i32x4*)(lds + (off)))
#define BAR() do { __builtin_amdgcn_s_barrier(); asm volatile("" ::: "memory"); } while (0)
#define LGKM0() do { asm volatile("s_waitcnt lgkmcnt(0)" ::: "memory");                 \
                     __builtin_amdgcn_sched_barrier(0); } while (0)
#define MFMAI(a_, b_, c_) __builtin_amdgcn_mfma_i32_16x16x64_i8((a_), (b_), (c_), 0, 0, 0)

  i32x4 acc[8][4];
  #pragma unroll
  for (int m = 0; m < 8; ++m)
    #pragma unroll
    for (int n = 0; n < 4; ++n)
      acc[m][n] = (i32x4){0, 0, 0, 0};

  // frag reads: 64B rows; lane reads 16B chunk g4 (k-bytes g4*16..+16), XOR (row>>1)&3
  const int s2 = (l15 >> 1) & 3;
  const int co = ((g4 ^ s2) << 4);
  const int aRow = (waveM * 128 + l15) * 64;            // + m*1024
  const int bRow = 16384 + (waveN * 64 + l15) * 64;     // + n*1024

  i32x4 af[4], bf[4];

  // prologue: stage tile 0 into buffer 0, drain, barrier
  STAGE_A(0, 0); STAGE_B(0, 0);
  asm volatile("s_waitcnt vmcnt(0)" ::: "memory");
  BAR();

  for (int t = 0; t < NKT; ++t) {
    const int cb = (t & 1) * 32768;
    const int nb = ((t + 1) & 1) * 32768;
    // ---- phase 0: Q(m0-3 x n0-1); 6 reads; stage A(t+1) ----
    #pragma unroll
    for (int m = 0; m < 4; ++m) af[m] = RD128(cb + aRow + m * 1024 + co);
    #pragma unroll
    for (int n = 0; n < 2; ++n) bf[n] = RD128(cb + bRow + n * 1024 + co);
    if (t + 1 < NKT) STAGE_A(t + 1, nb);
    BAR(); LGKM0();
    __builtin_amdgcn_s_setprio(1);
    #pragma unroll
    for (int m = 0; m < 4; ++m)
      #pragma unroll
      for (int n = 0; n < 2; ++n)
        acc[m][n] = MFMAI(af[m], bf[n], acc[m][n]);
    __builtin_amdgcn_s_setprio(0);
    BAR();
    // ---- phase 1: Q(m0-3 x n2-3); 2 reads; stage B(t+1) ----
    #pragma unroll
    for (int n = 2; n < 4; ++n) bf[n] = RD128(cb + bRow + n * 1024 + co);
    if (t + 1 < NKT) STAGE_B(t + 1, nb);
    BAR(); LGKM0();
    __builtin_amdgcn_s_setprio(1);
    #pragma unroll
    for (int m = 0; m < 4; ++m)
      #pragma unroll
      for (int n = 2; n < 4; ++n)
        acc[m][n] = MFMAI(af[m], bf[n], acc[m][n]);
    __builtin_amdgcn_s_setprio(0);
    BAR();
    // ---- phase 2: Q(m4-7 x n0-1); 4 reads (overwrite af) ----
    #pragma unroll
    for (int m = 0; m < 4; ++m) af[m] = RD128(cb + aRow + (m + 4) * 1024 + co);
    BAR(); LGKM0();
    __builtin_amdgcn_s_setprio(1);
    #pragma unroll
    for (int m = 0; m < 4; ++m)
      #pragma unroll
      for (int n = 0; n < 2; ++n)
        acc[m + 4][n] = MFMAI(af[m], bf[n], acc[m + 4][n]);
    __builtin_amdgcn_s_setprio(0);
    BAR();
    // ---- phase 3: Q(m4-7 x n2-3); no reads; tile-end drain ----
    __builtin_amdgcn_s_setprio(1);
    #pragma unroll
    for (int m = 0; m < 4; ++m)
      #pragma unroll
      for (int n = 2; n < 4; ++n)
        acc[m + 4][n] = MFMAI(af[m], bf[n], acc[m + 4][n]);
    __builtin_amdgcn_s_setprio(0);
    asm volatile("s_waitcnt vmcnt(0)" ::: "memory");
    BAR();
  }
#undef STAGE_A
#undef STAGE_B
#undef GLL
#undef RD128
#undef BAR
#undef LGKM0
#undef MFMAI

  // ---- fused epilogue: poincare dist via log2, exp-sums, dist sums ----
  const float lt = *p_log_tau;
  const float mg = *p_margin;
  const float marg = fmaxf(mg, 0.f);
  const float tau = 1.99f / (1.f + __expf(-lt)) + 0.01f;
  const float nl = -LN2F / tau;            // exp(L2*nl) == exp(-dist/tau)
  const float em = __expf(-marg);          // diagonal exp correction factor
  const bool diagblk = (bx == by);
  const float dq = 9.5367431640625e-07f;   // 2^-20: undo x1024 * x1024 (exact)

  float yyj[4], rcpy[4]; int gj[4];
  #pragma unroll
  for (int n = 0; n < 4; ++n) {
    gj[n] = blockCol + waveN * 64 + n * 16 + l15;        // C/D col = lane&15
    yyj[n] = yy[gj[n]];
    rcpy[n] = __builtin_amdgcn_rcpf(1.f - yyj[n]);
  }

  float dL = 0.f, dDiagL = 0.f;            // dist sums in log2 units
  float* rsum = (float*)lds;               // reuse LDS: [256 rows][4 waveN] partials

  #pragma unroll
  for (int m = 0; m < 8; ++m) {
    #pragma unroll
    for (int r = 0; r < 4; ++r) {
      const int gi = blockRow + waveM * 128 + m * 16 + g4 * 4 + r;  // C/D row
      const float xxi = xx[gi];
      const float p2 = 2.f * __builtin_amdgcn_rcpf(1.f - xxi);
      float e_acc = 0.f;
      #pragma unroll
      for (int n = 0; n < 4; ++n) {
        const float xy = (float)acc[m][n][r] * dq;
        const float sq = fmaxf(xxi + yyj[n] - 2.f * xy, 0.f);
        const float tt = sq * (p2 * rcpy[n]);            // arg = 1 + tt
        const float s = __builtin_amdgcn_sqrtf(tt * (tt + 2.f));
        const float w = tt + 1.f + s;                    // arg + sqrt(arg^2-1)
        const float L2 = __log2f(fmaxf(w, 1.f + EPSF));  // dist = L2 * ln2
        float e = __expf(L2 * nl);
        dL += L2;
        if (diagblk && gi == gj[n]) { dDiagL += L2; e *= em; }
        e_acc += e;
      }
      e_acc += __shfl_xor(e_acc, 1);
      e_acc += __shfl_xor(e_acc, 2);
      e_acc += __shfl_xor(e_acc, 4);
      e_acc += __shfl_xor(e_acc, 8);
      if (l15 == 0) {
        const int rloc = waveM * 128 + m * 16 + g4 * 4 + r;
        rsum[rloc * 4 + waveN] = e_acc;
      }
    }
  }

  // block-level scalar reductions -> 2 atomics per wave (log2 units)
  #pragma unroll
  for (int off = 32; off; off >>= 1) {
    dL += __shfl_down(dL, off);
    dDiagL += __shfl_down(dDiagL, off);
  }
  if (lane == 0) {
    atomicAdd(&accums[0], dL);
    if (diagblk) atomicAdd(&accums[1], dDiagL);
  }

  __syncthreads();
  if (tid < 256) {
    const float rs = rsum[tid * 4 + 0] + rsum[tid * 4 + 1] + rsum[tid * 4 + 2] + rsum[tid * 4 + 3];
    row_partial[(size_t)bx * BN + blockRow + tid] = rs;
  }
}

// ---------------- finalize: sum col-tile partials, log, final linear combo ----------------
__global__ __launch_bounds__(1024) void finalize_kernel(
    const float* __restrict__ row_partial, const float* __restrict__ accums,
    const float* __restrict__ p_log_tau, const float* __restrict__ p_margin,
    float* __restrict__ out) {
  const int t = threadIdx.x;
  float lsum = 0.f;
  for (int i = t; i < BN; i += 1024) {
    float s = 0.f;
    #pragma unroll
    for (int c = 0; c < 32; ++c) s += row_partial[(size_t)c * BN + i];
    lsum += __logf(s);
  }
  #pragma unroll
  for (int off = 32; off; off >>= 1) lsum += __shfl_down(lsum, off);
  __shared__ float red[16];
  if ((t & 63) == 0) red[t >> 6] = lsum;
  __syncthreads();
  if (t == 0) {
    float total = 0.f;
    #pragma unroll
    for (int w = 0; w < 16; ++w) total += red[w];
    const float lt = *p_log_tau;
    const float mg = *p_margin;
    const float marg = fmaxf(mg, 0.f);
    const float tau = 1.99f / (1.f + __expf(-lt)) + 0.01f;
    const float C = marg;
    const float d_tot = accums[0] * LN2F;
    const float d_diag = accums[1] * LN2F;
    const float bf = (float)BN;
    const float mean_lse = total / bf + C;
    const float sum_scores = -d_tot / tau + marg * (bf * bf - bf);  // margin closed-form
    const float sum_diag_scores = -d_diag / tau;
    const float loss = mean_lse
                     - (1.f - LSMOOTH) * (sum_diag_scores / bf)
                     - LSMOOTH * (sum_scores / (bf * bf));
    out[0] = loss;
    out[1] = d_diag / bf;   // pos_dist
    out[2] = tau;
    out[3] = mg;            // maximum(margin, margin) == margin
  }
}

extern "C" void kernel_launch(void* const* d_in, const int* in_sizes, int n_in,
                              void* d_out, int out_size, void* d_ws, size_t ws_size,
                              hipStream_t stream) {
  const float* sign = (const float*)d_in[0];
  const float* text = (const float*)d_in[1];
  const float* p_log_tau = (const float*)d_in[2];
  const float* p_margin = (const float*)d_in[3];
  float* out = (float*)d_out;

  char* ws = (char*)d_ws;
  uint8_t* Aq = (uint8_t*)ws;                                        // 8 MiB
  uint8_t* Bq = (uint8_t*)(ws + (size_t)BN * DK);                    // 8 MiB
  float* xx = (float*)(ws + (size_t)BN * DK * 2);
  float* yy = xx + BN;
  float* row_partial = yy + BN;                                      // 32 x 8192 floats
  float* accums = row_partial + 32 * BN;                             // 2 floats

  prep_kernel<<<dim3(2 * BN), 256, 0, stream>>>(sign, text, (uint32_t*)Aq, (uint32_t*)Bq,
                                                xx, yy, accums);
  gemm_fused<<<dim3(BN / 256, BN / 256), 512, 0, stream>>>(
      Aq, Bq, xx, yy, p_log_tau, p_margin, row_partial, accums);
  finalize_kernel<<<1, 1024, 0, stream>>>(row_partial, accums, p_log_tau, p_margin, out);
}

// Round 18
// 199.280 us; speedup vs baseline: 1.4276x; 1.0016x over previous
//
#include <hip/hip_runtime.h>
#include <hip/hip_bf16.h>
#include <stdint.h>

#define BN 8192
#define DK 1024
#define BKT 64                // K elements (= bytes) per tile
#define NKT (DK / BKT)        // 16 K-tiles
#define LSMOOTH 0.1f
#define EPSF 1e-7f
#define LN2F 0.69314718055994531f

typedef float f32x4 __attribute__((ext_vector_type(4)));
typedef int   i32x4 __attribute__((ext_vector_type(4)));

// ---------------- prep: f32 -> i8 (x1024, clamp +-127) + row norms + accums zero ------
__global__ __launch_bounds__(256) void prep_kernel(
    const float* __restrict__ sign, const float* __restrict__ text,
    uint32_t* __restrict__ Aq, uint32_t* __restrict__ Bq,
    float* __restrict__ xx, float* __restrict__ yy, float* __restrict__ accums) {
  const int b = blockIdx.x;          // 0..2*BN-1
  const int row = b & (BN - 1);
  const bool isB = b >= BN;
  const float4* src = (const float4*)((isB ? text : sign) + (size_t)row * DK);
  uint32_t* dst = (isB ? Bq : Aq) + (size_t)row * (DK / 4);
  const int t = threadIdx.x;         // 256 threads, 1 float4 each
  if (b == 0 && t < 2) accums[t] = 0.f;                 // fold memset into prep
  float4 v = src[t];
  int q0 = __float2int_rn(fminf(fmaxf(v.x * 1024.f, -127.f), 127.f));
  int q1 = __float2int_rn(fminf(fmaxf(v.y * 1024.f, -127.f), 127.f));
  int q2 = __float2int_rn(fminf(fmaxf(v.z * 1024.f, -127.f), 127.f));
  int q3 = __float2int_rn(fminf(fmaxf(v.w * 1024.f, -127.f), 127.f));
  dst[t] = (uint32_t)(q0 & 0xFF) | ((uint32_t)(q1 & 0xFF) << 8) |
           ((uint32_t)(q2 & 0xFF) << 16) | ((uint32_t)(q3 & 0xFF) << 24);
  float ss = v.x * v.x + v.y * v.y + v.z * v.z + v.w * v.w;  // norms exact f32
  #pragma unroll
  for (int off = 32; off; off >>= 1) ss += __shfl_down(ss, off);
  __shared__ float red[4];
  if ((t & 63) == 0) red[t >> 6] = ss;
  __syncthreads();
  if (t == 0) (isB ? yy : xx)[row] = red[0] + red[1] + red[2] + red[3];
}

// ---------------- fused GEMM: i8 16x16x64, 256x256 tile, BK=64, 2 buffers, 2 phases ---
// 8 waves (2M x 4N), per-wave 128x64. Per tile: ph0 {8 reads + stageA(t+1); bar; lgkm0;
// 16 MFMA m0-3 x n0-3; bar}, ph1 {4 reads + stageB(t+1); bar; lgkm0; 16 MFMA m4-7;
// vmcnt(0); bar}. 16 MFMA/phase = the measured-optimal granularity (R8 at bf16);
// barrier events per tile 8->4 vs R17. Staging/swizzle/dequant identical to R17.
__global__ __launch_bounds__(512, 2) void gemm_fused(
    const uint8_t* __restrict__ Aq, const uint8_t* __restrict__ Bq,
    const float* __restrict__ xx, const float* __restrict__ yy,
    const float* __restrict__ p_log_tau, const float* __restrict__ p_margin,
    float* __restrict__ row_partial, float* __restrict__ accums) {
  __shared__ __align__(16) char lds[65536];   // 2 buffers x (A 16KB + B 16KB)

  const int tid = threadIdx.x;
  const int wave = tid >> 6, lane = tid & 63;
  const int l15 = lane & 15, g4 = lane >> 4;
  const int waveM = wave >> 2, waveN = wave & 3;        // 2 x 4
  const int bx = blockIdx.x, by = blockIdx.y;
  const int blockRow = by * 256, blockCol = bx * 256;

  // staging: per GLL 512 threads cover 128 rows x 64B; thread t -> row t>>2,
  // 16B-chunk (t&3) ^ ((row>>1)&3) (pre-swizzled source; LDS written linearly by HW)
  const int srow = tid >> 2;                            // 0..127
  const int schunk = (tid & 3) ^ ((srow >> 1) & 3);     // involution
  const uint8_t* aSrc = Aq + (size_t)(blockRow + srow) * DK + schunk * 16;
  const uint8_t* bSrc = Bq + (size_t)(blockCol + srow) * DK + schunk * 16;
  const int ldst = wave * 1024;                         // wave-uniform base in 8KB call

#define GLL(gp, lp) __builtin_amdgcn_global_load_lds(                                   \
      (const __attribute__((address_space(1))) void*)(gp),                             \
      (__attribute__((address_space(3))) void*)(lp), 16, 0, 0)
#define STAGE_A(kt, cb) do { char* b_ = lds + (cb);                                     \
    const uint8_t* s_ = aSrc + (kt) * BKT;                                              \
    GLL(s_, b_ + ldst); GLL(s_ + 128 * DK, b_ + 8192 + ldst); } while (0)
#define STAGE_B(kt, cb) do { char* b_ = lds + (cb) + 16384;                             \
    const uint8_t* s_ = bSrc + (kt) * BKT;                                              \
    GLL(s_, b_ + ldst); GLL(s_ + 128 * DK, b_ + 8192 + ldst); } while (0)
#define RD128(off) (*(const i32x4*)(lds + (off)))
#define BAR() do { __builtin_amdgcn_s_barrier(); asm volatile("" ::: "memory"); } while (0)
#define LGKM0() do { asm volatile("s_waitcnt lgkmcnt(0)" ::: "memory");                 \
                     __builtin_amdgcn_sched_barrier(0); } while (0)
#define MFMAI(a_, b_, c_) __builtin_amdgcn_mfma_i32_16x16x64_i8((a_), (b_), (c_), 0, 0, 0)

  i32x4 acc[8][4];
  #pragma unroll
  for (int m = 0; m < 8; ++m)
    #pragma unroll
    for (int n = 0; n < 4; ++n)
      acc[m][n] = (i32x4){0, 0, 0, 0};

  // frag reads: 64B rows; lane reads 16B chunk g4 (k-bytes g4*16..+16), XOR (row>>1)&3
  const int s2 = (l15 >> 1) & 3;
  const int co = ((g4 ^ s2) << 4);
  const int aRow = (waveM * 128 + l15) * 64;            // + m*1024
  const int bRow = 16384 + (waveN * 64 + l15) * 64;     // + n*1024

  i32x4 af[4], bf[4];

  // prologue: stage tile 0 into buffer 0, drain, barrier
  STAGE_A(0, 0); STAGE_B(0, 0);
  asm volatile("s_waitcnt vmcnt(0)" ::: "memory");
  BAR();

  for (int t = 0; t < NKT; ++t) {
    const int cb = (t & 1) * 32768;
    const int nb = ((t + 1) & 1) * 32768;
    // ---- phase 0: m0-3 x n0-3 (16 MFMA); 8 reads; stage A(t+1) ----
    #pragma unroll
    for (int m = 0; m < 4; ++m) af[m] = RD128(cb + aRow + m * 1024 + co);
    #pragma unroll
    for (int n = 0; n < 4; ++n) bf[n] = RD128(cb + bRow + n * 1024 + co);
    if (t + 1 < NKT) STAGE_A(t + 1, nb);
    BAR(); LGKM0();
    __builtin_amdgcn_s_setprio(1);
    #pragma unroll
    for (int m = 0; m < 4; ++m)
      #pragma unroll
      for (int n = 0; n < 4; ++n)
        acc[m][n] = MFMAI(af[m], bf[n], acc[m][n]);
    __builtin_amdgcn_s_setprio(0);
    BAR();
    // ---- phase 1: m4-7 x n0-3 (16 MFMA); 4 reads (reuse af regs); stage B(t+1) ----
    #pragma unroll
    for (int m = 0; m < 4; ++m) af[m] = RD128(cb + aRow + (m + 4) * 1024 + co);
    if (t + 1 < NKT) STAGE_B(t + 1, nb);
    BAR(); LGKM0();
    __builtin_amdgcn_s_setprio(1);
    #pragma unroll
    for (int m = 0; m < 4; ++m)
      #pragma unroll
      for (int n = 0; n < 4; ++n)
        acc[m + 4][n] = MFMAI(af[m], bf[n], acc[m + 4][n]);
    __builtin_amdgcn_s_setprio(0);
    // drain this tile's GLLs (A issued ph0, B issued ph1) before buffers flip
    asm volatile("s_waitcnt vmcnt(0)" ::: "memory");
    BAR();
  }
#undef STAGE_A
#undef STAGE_B
#undef GLL
#undef RD128
#undef BAR
#undef LGKM0
#undef MFMAI

  // ---- fused epilogue: poincare dist via log2, exp-sums, dist sums ----
  const float lt = *p_log_tau;
  const float mg = *p_margin;
  const float marg = fmaxf(mg, 0.f);
  const float tau = 1.99f / (1.f + __expf(-lt)) + 0.01f;
  const float nl = -LN2F / tau;            // exp(L2*nl) == exp(-dist/tau)
  const float em = __expf(-marg);          // diagonal exp correction factor
  const bool diagblk = (bx == by);
  const float dq = 9.5367431640625e-07f;   // 2^-20: undo x1024 * x1024 (exact)

  float yyj[4], rcpy[4]; int gj[4];
  #pragma unroll
  for (int n = 0; n < 4; ++n) {
    gj[n] = blockCol + waveN * 64 + n * 16 + l15;        // C/D col = lane&15
    yyj[n] = yy[gj[n]];
    rcpy[n] = __builtin_amdgcn_rcpf(1.f - yyj[n]);
  }

  float dL = 0.f, dDiagL = 0.f;            // dist sums in log2 units
  float* rsum = (float*)lds;               // reuse LDS: [256 rows][4 waveN] partials

  #pragma unroll
  for (int m = 0; m < 8; ++m) {
    #pragma unroll
    for (int r = 0; r < 4; ++r) {
      const int gi = blockRow + waveM * 128 + m * 16 + g4 * 4 + r;  // C/D row
      const float xxi = xx[gi];
      const float p2 = 2.f * __builtin_amdgcn_rcpf(1.f - xxi);
      float e_acc = 0.f;
      #pragma unroll
      for (int n = 0; n < 4; ++n) {
        const float xy = (float)acc[m][n][r] * dq;
        const float sq = fmaxf(xxi + yyj[n] - 2.f * xy, 0.f);
        const float tt = sq * (p2 * rcpy[n]);            // arg = 1 + tt
        const float s = __builtin_amdgcn_sqrtf(tt * (tt + 2.f));
        const float w = tt + 1.f + s;                    // arg + sqrt(arg^2-1)
        const float L2 = __log2f(fmaxf(w, 1.f + EPSF));  // dist = L2 * ln2
        float e = __expf(L2 * nl);
        dL += L2;
        if (diagblk && gi == gj[n]) { dDiagL += L2; e *= em; }
        e_acc += e;
      }
      e_acc += __shfl_xor(e_acc, 1);
      e_acc += __shfl_xor(e_acc, 2);
      e_acc += __shfl_xor(e_acc, 4);
      e_acc += __shfl_xor(e_acc, 8);
      if (l15 == 0) {
        const int rloc = waveM * 128 + m * 16 + g4 * 4 + r;
        rsum[rloc * 4 + waveN] = e_acc;
      }
    }
  }

  // block-level scalar reductions -> 2 atomics per wave (log2 units)
  #pragma unroll
  for (int off = 32; off; off >>= 1) {
    dL += __shfl_down(dL, off);
    dDiagL += __shfl_down(dDiagL, off);
  }
  if (lane == 0) {
    atomicAdd(&accums[0], dL);
    if (diagblk) atomicAdd(&accums[1], dDiagL);
  }

  __syncthreads();
  if (tid < 256) {
    const float rs = rsum[tid * 4 + 0] + rsum[tid * 4 + 1] + rsum[tid * 4 + 2] + rsum[tid * 4 + 3];
    row_partial[(size_t)bx * BN + blockRow + tid] = rs;
  }
}

// ---------------- finalize: sum col-tile partials, log, final linear combo ----------------
__global__ __launch_bounds__(1024) void finalize_kernel(
    const float* __restrict__ row_partial, const float* __restrict__ accums,
    const float* __restrict__ p_log_tau, const float* __restrict__ p_margin,
    float* __restrict__ out) {
  const int t = threadIdx.x;
  float lsum = 0.f;
  for (int i = t; i < BN; i += 1024) {
    float s = 0.f;
    #pragma unroll
    for (int c = 0; c < 32; ++c) s += row_partial[(size_t)c * BN + i];
    lsum += __logf(s);
  }
  #pragma unroll
  for (int off = 32; off; off >>= 1) lsum += __shfl_down(lsum, off);
  __shared__ float red[16];
  if ((t & 63) == 0) red[t >> 6] = lsum;
  __syncthreads();
  if (t == 0) {
    float total = 0.f;
    #pragma unroll
    for (int w = 0; w < 16; ++w) total += red[w];
    const float lt = *p_log_tau;
    const float mg = *p_margin;
    const float marg = fmaxf(mg, 0.f);
    const float tau = 1.99f / (1.f + __expf(-lt)) + 0.01f;
    const float C = marg;
    const float d_tot = accums[0] * LN2F;
    const float d_diag = accums[1] * LN2F;
    const float bf = (float)BN;
    const float mean_lse = total / bf + C;
    const float sum_scores = -d_tot / tau + marg * (bf * bf - bf);  // margin closed-form
    const float sum_diag_scores = -d_diag / tau;
    const float loss = mean_lse
                     - (1.f - LSMOOTH) * (sum_diag_scores / bf)
                     - LSMOOTH * (sum_scores / (bf * bf));
    out[0] = loss;
    out[1] = d_diag / bf;   // pos_dist
    out[2] = tau;
    out[3] = mg;            // maximum(margin, margin) == margin
  }
}

extern "C" void kernel_launch(void* const* d_in, const int* in_sizes, int n_in,
                              void* d_out, int out_size, void* d_ws, size_t ws_size,
                              hipStream_t stream) {
  const float* sign = (const float*)d_in[0];
  const float* text = (const float*)d_in[1];
  const float* p_log_tau = (const float*)d_in[2];
  const float* p_margin = (const float*)d_in[3];
  float* out = (float*)d_out;

  char* ws = (char*)d_ws;
  uint8_t* Aq = (uint8_t*)ws;                                        // 8 MiB
  uint8_t* Bq = (uint8_t*)(ws + (size_t)BN * DK);                    // 8 MiB
  float* xx = (float*)(ws + (size_t)BN * DK * 2);
  float* yy = xx + BN;
  float* row_partial = yy + BN;                                      // 32 x 8192 floats
  float* accums = row_partial + 32 * BN;                             // 2 floats

  prep_kernel<<<dim3(2 * BN), 256, 0, stream>>>(sign, text, (uint32_t*)Aq, (uint32_t*)Bq,
                                                xx, yy, accums);
  gemm_fused<<<dim3(BN / 256, BN / 256), 512, 0, stream>>>(
      Aq, Bq, xx, yy, p_log_tau, p_margin, row_partial, accums);
  finalize_kernel<<<1, 1024, 0, stream>>>(row_partial, accums, p_log_tau, p_margin, out);
}

// Round 19
// 192.380 us; speedup vs baseline: 1.4788x; 1.0359x over previous
//
#include <hip/hip_runtime.h>
#include <hip/hip_bf16.h>
#include <stdint.h>

#define BN 8192
#define DK 1024
#define BKT 64                // K elements (= bytes) per tile
#define NKT (DK / BKT)        // 16 K-tiles
#define LSMOOTH 0.1f
#define EPSF 1e-7f
#define LN2F 0.69314718055994531f

typedef float f32x4 __attribute__((ext_vector_type(4)));
typedef int   i32x4 __attribute__((ext_vector_type(4)));

// ---------------- prep: f32 -> i8 (x1024, clamp +-127) + row norms + accums zero ------
__global__ __launch_bounds__(256) void prep_kernel(
    const float* __restrict__ sign, const float* __restrict__ text,
    uint32_t* __restrict__ Aq, uint32_t* __restrict__ Bq,
    float* __restrict__ xx, float* __restrict__ yy, float* __restrict__ accums) {
  const int b = blockIdx.x;          // 0..2*BN-1
  const int row = b & (BN - 1);
  const bool isB = b >= BN;
  const float4* src = (const float4*)((isB ? text : sign) + (size_t)row * DK);
  uint32_t* dst = (isB ? Bq : Aq) + (size_t)row * (DK / 4);
  const int t = threadIdx.x;         // 256 threads, 1 float4 each
  if (b == 0 && t < 3) accums[t] = 0.f;                 // fold memset into prep
  float4 v = src[t];
  int q0 = __float2int_rn(fminf(fmaxf(v.x * 1024.f, -127.f), 127.f));
  int q1 = __float2int_rn(fminf(fmaxf(v.y * 1024.f, -127.f), 127.f));
  int q2 = __float2int_rn(fminf(fmaxf(v.z * 1024.f, -127.f), 127.f));
  int q3 = __float2int_rn(fminf(fmaxf(v.w * 1024.f, -127.f), 127.f));
  dst[t] = (uint32_t)(q0 & 0xFF) | ((uint32_t)(q1 & 0xFF) << 8) |
           ((uint32_t)(q2 & 0xFF) << 16) | ((uint32_t)(q3 & 0xFF) << 24);
  float ss = v.x * v.x + v.y * v.y + v.z * v.z + v.w * v.w;  // norms exact f32
  #pragma unroll
  for (int off = 32; off; off >>= 1) ss += __shfl_down(ss, off);
  __shared__ float red[4];
  if ((t & 63) == 0) red[t >> 6] = ss;
  __syncthreads();
  if (t == 0) (isB ? yy : xx)[row] = red[0] + red[1] + red[2] + red[3];
}

// ---------------- fused GEMM: i8 16x16x64, 256x256 tile, BK=64, 2 buffers, 4 phases ---
// (R17 loop — measured best at 176.7 us.) 8 waves (2M x 4N), per-wave 128x64,
// mfma_i32_16x16x64_i8: i32x4 operands (one b128 read each), exact integer dots,
// dequant 2^-20 in epilogue. Phases: {6rd+stageA}, {2rd+stageB}, {4rd}, {0rd+drain}.
__global__ __launch_bounds__(512, 2) void gemm_fused(
    const uint8_t* __restrict__ Aq, const uint8_t* __restrict__ Bq,
    const float* __restrict__ xx, const float* __restrict__ yy,
    const float* __restrict__ p_log_tau, const float* __restrict__ p_margin,
    float* __restrict__ row_partial, float* __restrict__ accums) {
  __shared__ __align__(16) char lds[65536];   // 2 buffers x (A 16KB + B 16KB)

  const int tid = threadIdx.x;
  const int wave = tid >> 6, lane = tid & 63;
  const int l15 = lane & 15, g4 = lane >> 4;
  const int waveM = wave >> 2, waveN = wave & 3;        // 2 x 4
  const int bx = blockIdx.x, by = blockIdx.y;
  const int blockRow = by * 256, blockCol = bx * 256;

  // staging: per GLL 512 threads cover 128 rows x 64B; thread t -> row t>>2,
  // 16B-chunk (t&3) ^ ((row>>1)&3) (pre-swizzled source; LDS written linearly by HW)
  const int srow = tid >> 2;                            // 0..127
  const int schunk = (tid & 3) ^ ((srow >> 1) & 3);     // involution
  const uint8_t* aSrc = Aq + (size_t)(blockRow + srow) * DK + schunk * 16;
  const uint8_t* bSrc = Bq + (size_t)(blockCol + srow) * DK + schunk * 16;
  const int ldst = wave * 1024;                         // wave-uniform base in 8KB call

#define GLL(gp, lp) __builtin_amdgcn_global_load_lds(                                   \
      (const __attribute__((address_space(1))) void*)(gp),                             \
      (__attribute__((address_space(3))) void*)(lp), 16, 0, 0)
#define STAGE_A(kt, cb) do { char* b_ = lds + (cb);                                     \
    const uint8_t* s_ = aSrc + (kt) * BKT;                                              \
    GLL(s_, b_ + ldst); GLL(s_ + 128 * DK, b_ + 8192 + ldst); } while (0)
#define STAGE_B(kt, cb) do { char* b_ = lds + (cb) + 16384;                             \
    const uint8_t* s_ = bSrc + (kt) * BKT;                                              \
    GLL(s_, b_ + ldst); GLL(s_ + 128 * DK, b_ + 8192 + ldst); } while (0)
#define RD128(off) (*(const i32x4*)(lds + (off)))
#define BAR() do { __builtin_amdgcn_s_barrier(); asm volatile("" ::: "memory"); } while (0)
#define LGKM0() do { asm volatile("s_waitcnt lgkmcnt(0)" ::: "memory");                 \
                     __builtin_amdgcn_sched_barrier(0); } while (0)
#define MFMAI(a_, b_, c_) __builtin_amdgcn_mfma_i32_16x16x64_i8((a_), (b_), (c_), 0, 0, 0)

  i32x4 acc[8][4];
  #pragma unroll
  for (int m = 0; m < 8; ++m)
    #pragma unroll
    for (int n = 0; n < 4; ++n)
      acc[m][n] = (i32x4){0, 0, 0, 0};

  // frag reads: 64B rows; lane reads 16B chunk g4 (k-bytes g4*16..+16), XOR (row>>1)&3
  const int s2 = (l15 >> 1) & 3;
  const int co = ((g4 ^ s2) << 4);
  const int aRow = (waveM * 128 + l15) * 64;            // + m*1024
  const int bRow = 16384 + (waveN * 64 + l15) * 64;     // + n*1024

  i32x4 af[4], bf[4];

  // prologue: stage tile 0 into buffer 0, drain, barrier
  STAGE_A(0, 0); STAGE_B(0, 0);
  asm volatile("s_waitcnt vmcnt(0)" ::: "memory");
  BAR();

  for (int t = 0; t < NKT; ++t) {
    const int cb = (t & 1) * 32768;
    const int nb = ((t + 1) & 1) * 32768;
    // ---- phase 0: Q(m0-3 x n0-1); 6 reads; stage A(t+1) ----
    #pragma unroll
    for (int m = 0; m < 4; ++m) af[m] = RD128(cb + aRow + m * 1024 + co);
    #pragma unroll
    for (int n = 0; n < 2; ++n) bf[n] = RD128(cb + bRow + n * 1024 + co);
    if (t + 1 < NKT) STAGE_A(t + 1, nb);
    BAR(); LGKM0();
    __builtin_amdgcn_s_setprio(1);
    #pragma unroll
    for (int m = 0; m < 4; ++m)
      #pragma unroll
      for (int n = 0; n < 2; ++n)
        acc[m][n] = MFMAI(af[m], bf[n], acc[m][n]);
    __builtin_amdgcn_s_setprio(0);
    BAR();
    // ---- phase 1: Q(m0-3 x n2-3); 2 reads; stage B(t+1) ----
    #pragma unroll
    for (int n = 2; n < 4; ++n) bf[n] = RD128(cb + bRow + n * 1024 + co);
    if (t + 1 < NKT) STAGE_B(t + 1, nb);
    BAR(); LGKM0();
    __builtin_amdgcn_s_setprio(1);
    #pragma unroll
    for (int m = 0; m < 4; ++m)
      #pragma unroll
      for (int n = 2; n < 4; ++n)
        acc[m][n] = MFMAI(af[m], bf[n], acc[m][n]);
    __builtin_amdgcn_s_setprio(0);
    BAR();
    // ---- phase 2: Q(m4-7 x n0-1); 4 reads (overwrite af) ----
    #pragma unroll
    for (int m = 0; m < 4; ++m) af[m] = RD128(cb + aRow + (m + 4) * 1024 + co);
    BAR(); LGKM0();
    __builtin_amdgcn_s_setprio(1);
    #pragma unroll
    for (int m = 0; m < 4; ++m)
      #pragma unroll
      for (int n = 0; n < 2; ++n)
        acc[m + 4][n] = MFMAI(af[m], bf[n], acc[m + 4][n]);
    __builtin_amdgcn_s_setprio(0);
    BAR();
    // ---- phase 3: Q(m4-7 x n2-3); no reads; tile-end drain ----
    __builtin_amdgcn_s_setprio(1);
    #pragma unroll
    for (int m = 0; m < 4; ++m)
      #pragma unroll
      for (int n = 2; n < 4; ++n)
        acc[m + 4][n] = MFMAI(af[m], bf[n], acc[m + 4][n]);
    __builtin_amdgcn_s_setprio(0);
    asm volatile("s_waitcnt vmcnt(0)" ::: "memory");
    BAR();
  }
#undef STAGE_A
#undef STAGE_B
#undef GLL
#undef RD128
#undef BAR
#undef LGKM0
#undef MFMAI

  // ---- fused epilogue: poincare dist via log2, exp-sums, dist sums ----
  const float lt = *p_log_tau;
  const float mg = *p_margin;
  const float marg = fmaxf(mg, 0.f);
  const float tau = 1.99f / (1.f + __expf(-lt)) + 0.01f;
  const float nl = -LN2F / tau;            // exp(L2*nl) == exp(-dist/tau)
  const float em = __expf(-marg);          // diagonal exp correction factor
  const bool diagblk = (bx == by);
  const float dq = 9.5367431640625e-07f;   // 2^-20: undo x1024 * x1024 (exact)

  float yyj[4], rcpy[4]; int gj[4];
  #pragma unroll
  for (int n = 0; n < 4; ++n) {
    gj[n] = blockCol + waveN * 64 + n * 16 + l15;        // C/D col = lane&15
    yyj[n] = yy[gj[n]];
    rcpy[n] = __builtin_amdgcn_rcpf(1.f - yyj[n]);
  }

  float dL = 0.f, dDiagL = 0.f;            // dist sums in log2 units
  float* rsum = (float*)lds;               // reuse LDS: [256 rows][4 waveN] partials

  #pragma unroll
  for (int m = 0; m < 8; ++m) {
    #pragma unroll
    for (int r = 0; r < 4; ++r) {
      const int gi = blockRow + waveM * 128 + m * 16 + g4 * 4 + r;  // C/D row
      const float xxi = xx[gi];
      const float p2 = 2.f * __builtin_amdgcn_rcpf(1.f - xxi);
      float e_acc = 0.f;
      #pragma unroll
      for (int n = 0; n < 4; ++n) {
        const float xy = (float)acc[m][n][r] * dq;
        const float sq = fmaxf(xxi + yyj[n] - 2.f * xy, 0.f);
        const float tt = sq * (p2 * rcpy[n]);            // arg = 1 + tt
        const float s = __builtin_amdgcn_sqrtf(tt * (tt + 2.f));
        const float w = tt + 1.f + s;                    // arg + sqrt(arg^2-1)
        const float L2 = __log2f(fmaxf(w, 1.f + EPSF));  // dist = L2 * ln2
        float e = __expf(L2 * nl);
        dL += L2;
        if (diagblk && gi == gj[n]) { dDiagL += L2; e *= em; }
        e_acc += e;
      }
      e_acc += __shfl_xor(e_acc, 1);
      e_acc += __shfl_xor(e_acc, 2);
      e_acc += __shfl_xor(e_acc, 4);
      e_acc += __shfl_xor(e_acc, 8);
      if (l15 == 0) {
        const int rloc = waveM * 128 + m * 16 + g4 * 4 + r;
        rsum[rloc * 4 + waveN] = e_acc;
      }
    }
  }

  // block-level scalar reductions -> 2 atomics per wave (log2 units)
  #pragma unroll
  for (int off = 32; off; off >>= 1) {
    dL += __shfl_down(dL, off);
    dDiagL += __shfl_down(dDiagL, off);
  }
  if (lane == 0) {
    atomicAdd(&accums[0], dL);
    if (diagblk) atomicAdd(&accums[1], dDiagL);
  }

  __syncthreads();
  if (tid < 256) {
    const float rs = rsum[tid * 4 + 0] + rsum[tid * 4 + 1] + rsum[tid * 4 + 2] + rsum[tid * 4 + 3];
    row_partial[(size_t)bx * BN + blockRow + tid] = rs;
  }
}

// ---------------- logsum: per-row sum of 32 col-tile partials, log, block-reduce ------
// 32 blocks x 256 threads: coalesced reads (consecutive threads -> consecutive rows).
__global__ __launch_bounds__(256) void logsum_kernel(
    const float* __restrict__ row_partial, float* __restrict__ accums) {
  const int row = blockIdx.x * 256 + threadIdx.x;       // 32 x 256 = 8192 rows
  float s = 0.f;
  #pragma unroll
  for (int c = 0; c < 32; ++c) s += row_partial[(size_t)c * BN + row];
  float lsum = __logf(s);
  #pragma unroll
  for (int off = 32; off; off >>= 1) lsum += __shfl_down(lsum, off);
  __shared__ float red[4];
  if ((threadIdx.x & 63) == 0) red[threadIdx.x >> 6] = lsum;
  __syncthreads();
  if (threadIdx.x == 0)
    atomicAdd(&accums[2], red[0] + red[1] + red[2] + red[3]);
}

// ---------------- final: linear combination ----------------
__global__ void final_kernel(
    const float* __restrict__ accums,
    const float* __restrict__ p_log_tau, const float* __restrict__ p_margin,
    float* __restrict__ out) {
  const float lt = *p_log_tau;
  const float mg = *p_margin;
  const float marg = fmaxf(mg, 0.f);
  const float tau = 1.99f / (1.f + __expf(-lt)) + 0.01f;
  const float C = marg;
  const float d_tot = accums[0] * LN2F;
  const float d_diag = accums[1] * LN2F;
  const float bf = (float)BN;
  const float mean_lse = accums[2] / bf + C;
  const float sum_scores = -d_tot / tau + marg * (bf * bf - bf);  // margin closed-form
  const float sum_diag_scores = -d_diag / tau;
  const float loss = mean_lse
                   - (1.f - LSMOOTH) * (sum_diag_scores / bf)
                   - LSMOOTH * (sum_scores / (bf * bf));
  out[0] = loss;
  out[1] = d_diag / bf;   // pos_dist
  out[2] = tau;
  out[3] = mg;            // maximum(margin, margin) == margin
}

extern "C" void kernel_launch(void* const* d_in, const int* in_sizes, int n_in,
                              void* d_out, int out_size, void* d_ws, size_t ws_size,
                              hipStream_t stream) {
  const float* sign = (const float*)d_in[0];
  const float* text = (const float*)d_in[1];
  const float* p_log_tau = (const float*)d_in[2];
  const float* p_margin = (const float*)d_in[3];
  float* out = (float*)d_out;

  char* ws = (char*)d_ws;
  uint8_t* Aq = (uint8_t*)ws;                                        // 8 MiB
  uint8_t* Bq = (uint8_t*)(ws + (size_t)BN * DK);                    // 8 MiB
  float* xx = (float*)(ws + (size_t)BN * DK * 2);
  float* yy = xx + BN;
  float* row_partial = yy + BN;                                      // 32 x 8192 floats
  float* accums = row_partial + 32 * BN;                             // 3 floats

  prep_kernel<<<dim3(2 * BN), 256, 0, stream>>>(sign, text, (uint32_t*)Aq, (uint32_t*)Bq,
                                                xx, yy, accums);
  gemm_fused<<<dim3(BN / 256, BN / 256), 512, 0, stream>>>(
      Aq, Bq, xx, yy, p_log_tau, p_margin, row_partial, accums);
  logsum_kernel<<<dim3(BN / 256), 256, 0, stream>>>(row_partial, accums);
  final_kernel<<<1, 1, 0, stream>>>(accums, p_log_tau, p_margin, out);
}

// Round 20
// 189.772 us; speedup vs baseline: 1.4991x; 1.0137x over previous
//
#include <hip/hip_runtime.h>
#include <hip/hip_bf16.h>
#include <stdint.h>

#define BN 8192
#define DK 1024
#define BKT 64                // K elements (= bytes) per tile
#define NKT (DK / BKT)        // 16 K-tiles
#define LSMOOTH 0.1f
#define EPSF 1e-7f
#define LN2F 0.69314718055994531f

typedef float f32x4 __attribute__((ext_vector_type(4)));
typedef int   i32x4 __attribute__((ext_vector_type(4)));

// ---------------- prep: f32 -> i8 (x1024, clamp +-127) + row norms + accums zero ------
__global__ __launch_bounds__(256) void prep_kernel(
    const float* __restrict__ sign, const float* __restrict__ text,
    uint32_t* __restrict__ Aq, uint32_t* __restrict__ Bq,
    float* __restrict__ xx, float* __restrict__ yy, float* __restrict__ accums) {
  const int b = blockIdx.x;          // 0..2*BN-1
  const int row = b & (BN - 1);
  const bool isB = b >= BN;
  const float4* src = (const float4*)((isB ? text : sign) + (size_t)row * DK);
  uint32_t* dst = (isB ? Bq : Aq) + (size_t)row * (DK / 4);
  const int t = threadIdx.x;         // 256 threads, 1 float4 each
  if (b == 0 && t < 3) accums[t] = 0.f;                 // fold memset into prep
  float4 v = src[t];
  int q0 = __float2int_rn(fminf(fmaxf(v.x * 1024.f, -127.f), 127.f));
  int q1 = __float2int_rn(fminf(fmaxf(v.y * 1024.f, -127.f), 127.f));
  int q2 = __float2int_rn(fminf(fmaxf(v.z * 1024.f, -127.f), 127.f));
  int q3 = __float2int_rn(fminf(fmaxf(v.w * 1024.f, -127.f), 127.f));
  dst[t] = (uint32_t)(q0 & 0xFF) | ((uint32_t)(q1 & 0xFF) << 8) |
           ((uint32_t)(q2 & 0xFF) << 16) | ((uint32_t)(q3 & 0xFF) << 24);
  float ss = v.x * v.x + v.y * v.y + v.z * v.z + v.w * v.w;  // norms exact f32
  #pragma unroll
  for (int off = 32; off; off >>= 1) ss += __shfl_down(ss, off);
  __shared__ float red[4];
  if ((t & 63) == 0) red[t >> 6] = ss;
  __syncthreads();
  if (t == 0) (isB ? yy : xx)[row] = red[0] + red[1] + red[2] + red[3];
}

// ---------------- fused GEMM: i8, 256x256, BK=64, 2 buffers, ONE barrier per tile -----
// 8 waves (2M x 4N), per-wave 128x64. Intra-tile sync is counted lgkm only (no barriers
// — GLLs write the other buffer, so reads never race writes); one vmcnt(0)+s_barrier
// per tile publishes the next buffer. Reads are pinned with sched_barrier(0) on BOTH
// sides so the compiler can neither sink prefetches nor hoist MFMA (rule #18 + dual):
//   ph0: stage(t+1,nb); read af-hi; [fence] lgkm(4) -> Q0,Q1 (af-lo x bf) overlap af-hi
//   ph1: lgkm(0) -> Q2 (af-hi x bf-lo); vmcnt(0)+BAR; read S0(t+1) from nb; [fence]
//        Q3 (af-hi x bf-hi) overlaps next tile's 12 reads.
__global__ __launch_bounds__(512, 1) void gemm_fused(
    const uint8_t* __restrict__ Aq, const uint8_t* __restrict__ Bq,
    const float* __restrict__ xx, const float* __restrict__ yy,
    const float* __restrict__ p_log_tau, const float* __restrict__ p_margin,
    float* __restrict__ row_partial, float* __restrict__ accums) {
  __shared__ __align__(16) char lds[65536];   // 2 buffers x (A 16KB + B 16KB)

  const int tid = threadIdx.x;
  const int wave = tid >> 6, lane = tid & 63;
  const int l15 = lane & 15, g4 = lane >> 4;
  const int waveM = wave >> 2, waveN = wave & 3;        // 2 x 4
  const int bx = blockIdx.x, by = blockIdx.y;
  const int blockRow = by * 256, blockCol = bx * 256;

  // staging: per GLL 512 threads cover 128 rows x 64B; thread t -> row t>>2,
  // 16B-chunk (t&3) ^ ((row>>1)&3) (pre-swizzled source; LDS written linearly by HW)
  const int srow = tid >> 2;                            // 0..127
  const int schunk = (tid & 3) ^ ((srow >> 1) & 3);     // involution
  const uint8_t* aSrc = Aq + (size_t)(blockRow + srow) * DK + schunk * 16;
  const uint8_t* bSrc = Bq + (size_t)(blockCol + srow) * DK + schunk * 16;
  const int ldst = wave * 1024;                         // wave-uniform base in 8KB call

#define GLL(gp, lp) __builtin_amdgcn_global_load_lds(                                   \
      (const __attribute__((address_space(1))) void*)(gp),                             \
      (__attribute__((address_space(3))) void*)(lp), 16, 0, 0)
#define STAGE_A(kt, cb) do { char* b_ = lds + (cb);                                     \
    const uint8_t* s_ = aSrc + (kt) * BKT;                                              \
    GLL(s_, b_ + ldst); GLL(s_ + 128 * DK, b_ + 8192 + ldst); } while (0)
#define STAGE_B(kt, cb) do { char* b_ = lds + (cb) + 16384;                             \
    const uint8_t* s_ = bSrc + (kt) * BKT;                                              \
    GLL(s_, b_ + ldst); GLL(s_ + 128 * DK, b_ + 8192 + ldst); } while (0)
#define RD128(off) (*(const i32x4*)(lds + (off)))
#define FENCE() __builtin_amdgcn_sched_barrier(0)
#define MFMAI(a_, b_, c_) __builtin_amdgcn_mfma_i32_16x16x64_i8((a_), (b_), (c_), 0, 0, 0)

  i32x4 acc[8][4];
  #pragma unroll
  for (int m = 0; m < 8; ++m)
    #pragma unroll
    for (int n = 0; n < 4; ++n)
      acc[m][n] = (i32x4){0, 0, 0, 0};

  // frag reads: 64B rows; lane reads 16B chunk g4 (k-bytes g4*16..+16), XOR (row>>1)&3
  const int s2 = (l15 >> 1) & 3;
  const int co = ((g4 ^ s2) << 4);
  const int aRow = (waveM * 128 + l15) * 64;            // + m*1024
  const int bRow = 16384 + (waveN * 64 + l15) * 64;     // + n*1024

  i32x4 af[4], ah[4], bf[4], bfN[4];

  // prologue: stage tile 0, publish, read S0(0) = {af-lo, bf}
  STAGE_A(0, 0); STAGE_B(0, 0);
  asm volatile("s_waitcnt vmcnt(0)" ::: "memory");
  __builtin_amdgcn_s_barrier();
  asm volatile("" ::: "memory");
  #pragma unroll
  for (int m = 0; m < 4; ++m) af[m] = RD128(aRow + m * 1024 + co);
  #pragma unroll
  for (int n = 0; n < 4; ++n) bf[n] = RD128(bRow + n * 1024 + co);

  for (int t = 0; t < NKT; ++t) {
    const int cb = (t & 1) * 32768;
    const int nb = ((t + 1) & 1) * 32768;
    const bool more = (t + 1 < NKT);
    // ---- ph0: stage t+1 (other buffer); prefetch af-hi; Q0+Q1 on S0 frags ----
    if (more) { STAGE_A(t + 1, nb); STAGE_B(t + 1, nb); }
    #pragma unroll
    for (int m = 0; m < 4; ++m) ah[m] = RD128(cb + aRow + (m + 4) * 1024 + co);
    FENCE();
    asm volatile("s_waitcnt lgkmcnt(4)" ::: "memory");   // drain S0; ah stays in flight
    FENCE();
    __builtin_amdgcn_s_setprio(1);
    #pragma unroll
    for (int m = 0; m < 4; ++m)
      #pragma unroll
      for (int n = 0; n < 4; ++n)
        acc[m][n] = MFMAI(af[m], bf[n], acc[m][n]);      // Q0+Q1: 16 MFMA over ah reads
    __builtin_amdgcn_s_setprio(0);
    // ---- ph1: Q2; publish t+1; prefetch S0(t+1); Q3 over those reads ----
    asm volatile("s_waitcnt lgkmcnt(0)" ::: "memory");   // ah ready
    FENCE();
    __builtin_amdgcn_s_setprio(1);
    #pragma unroll
    for (int m = 0; m < 4; ++m)
      #pragma unroll
      for (int n = 0; n < 2; ++n)
        acc[m + 4][n] = MFMAI(ah[m], bf[n], acc[m + 4][n]);   // Q2: 8 MFMA
    __builtin_amdgcn_s_setprio(0);
    if (more) {
      asm volatile("s_waitcnt vmcnt(0)" ::: "memory");   // t+1's 4 GLL landed (L2-fast)
      __builtin_amdgcn_s_barrier();                      // the ONLY barrier this tile
      asm volatile("" ::: "memory");
      #pragma unroll
      for (int m = 0; m < 4; ++m) af[m] = RD128(nb + aRow + m * 1024 + co);
      #pragma unroll
      for (int n = 0; n < 4; ++n) bfN[n] = RD128(nb + bRow + n * 1024 + co);
      FENCE();                                           // pin reads above Q3
    }
    __builtin_amdgcn_s_setprio(1);
    #pragma unroll
    for (int m = 0; m < 4; ++m)
      #pragma unroll
      for (int n = 2; n < 4; ++n)
        acc[m + 4][n] = MFMAI(ah[m], bf[n], acc[m + 4][n]);   // Q3: 8 MFMA over 12 reads
    __builtin_amdgcn_s_setprio(0);
    if (more) {
      #pragma unroll
      for (int n = 0; n < 4; ++n) bf[n] = bfN[n];
    }
  }
  __syncthreads();   // all waves out of the K-loop before LDS is reused for rsum
#undef STAGE_A
#undef STAGE_B
#undef GLL
#undef RD128
#undef FENCE
#undef MFMAI

  // ---- fused epilogue: poincare dist via log2, exp-sums, dist sums ----
  const float lt = *p_log_tau;
  const float mg = *p_margin;
  const float marg = fmaxf(mg, 0.f);
  const float tau = 1.99f / (1.f + __expf(-lt)) + 0.01f;
  const float nl = -LN2F / tau;            // exp(L2*nl) == exp(-dist/tau)
  const float em = __expf(-marg);          // diagonal exp correction factor
  const bool diagblk = (bx == by);
  const float dq = 9.5367431640625e-07f;   // 2^-20: undo x1024 * x1024 (exact)

  float yyj[4], rcpy[4]; int gj[4];
  #pragma unroll
  for (int n = 0; n < 4; ++n) {
    gj[n] = blockCol + waveN * 64 + n * 16 + l15;        // C/D col = lane&15
    yyj[n] = yy[gj[n]];
    rcpy[n] = __builtin_amdgcn_rcpf(1.f - yyj[n]);
  }

  float dL = 0.f, dDiagL = 0.f;            // dist sums in log2 units
  float* rsum = (float*)lds;               // reuse LDS: [256 rows][4 waveN] partials

  #pragma unroll
  for (int m = 0; m < 8; ++m) {
    #pragma unroll
    for (int r = 0; r < 4; ++r) {
      const int gi = blockRow + waveM * 128 + m * 16 + g4 * 4 + r;  // C/D row
      const float xxi = xx[gi];
      const float p2 = 2.f * __builtin_amdgcn_rcpf(1.f - xxi);
      float e_acc = 0.f;
      #pragma unroll
      for (int n = 0; n < 4; ++n) {
        const float xy = (float)acc[m][n][r] * dq;
        const float sq = fmaxf(xxi + yyj[n] - 2.f * xy, 0.f);
        const float tt = sq * (p2 * rcpy[n]);            // arg = 1 + tt
        const float s = __builtin_amdgcn_sqrtf(tt * (tt + 2.f));
        const float w = tt + 1.f + s;                    // arg + sqrt(arg^2-1)
        const float L2 = __log2f(fmaxf(w, 1.f + EPSF));  // dist = L2 * ln2
        float e = __expf(L2 * nl);
        dL += L2;
        if (diagblk && gi == gj[n]) { dDiagL += L2; e *= em; }
        e_acc += e;
      }
      e_acc += __shfl_xor(e_acc, 1);
      e_acc += __shfl_xor(e_acc, 2);
      e_acc += __shfl_xor(e_acc, 4);
      e_acc += __shfl_xor(e_acc, 8);
      if (l15 == 0) {
        const int rloc = waveM * 128 + m * 16 + g4 * 4 + r;
        rsum[rloc * 4 + waveN] = e_acc;
      }
    }
  }

  // block-level scalar reductions -> 2 atomics per wave (log2 units)
  #pragma unroll
  for (int off = 32; off; off >>= 1) {
    dL += __shfl_down(dL, off);
    dDiagL += __shfl_down(dDiagL, off);
  }
  if (lane == 0) {
    atomicAdd(&accums[0], dL);
    if (diagblk) atomicAdd(&accums[1], dDiagL);
  }

  __syncthreads();
  if (tid < 256) {
    const float rs = rsum[tid * 4 + 0] + rsum[tid * 4 + 1] + rsum[tid * 4 + 2] + rsum[tid * 4 + 3];
    row_partial[(size_t)bx * BN + blockRow + tid] = rs;
  }
}

// ---------------- logsum: per-row sum of 32 col-tile partials, log, block-reduce ------
__global__ __launch_bounds__(256) void logsum_kernel(
    const float* __restrict__ row_partial, float* __restrict__ accums) {
  const int row = blockIdx.x * 256 + threadIdx.x;       // 32 x 256 = 8192 rows
  float s = 0.f;
  #pragma unroll
  for (int c = 0; c < 32; ++c) s += row_partial[(size_t)c * BN + row];
  float lsum = __logf(s);
  #pragma unroll
  for (int off = 32; off; off >>= 1) lsum += __shfl_down(lsum, off);
  __shared__ float red[4];
  if ((threadIdx.x & 63) == 0) red[threadIdx.x >> 6] = lsum;
  __syncthreads();
  if (threadIdx.x == 0)
    atomicAdd(&accums[2], red[0] + red[1] + red[2] + red[3]);
}

// ---------------- final: linear combination ----------------
__global__ void final_kernel(
    const float* __restrict__ accums,
    const float* __restrict__ p_log_tau, const float* __restrict__ p_margin,
    float* __restrict__ out) {
  const float lt = *p_log_tau;
  const float mg = *p_margin;
  const float marg = fmaxf(mg, 0.f);
  const float tau = 1.99f / (1.f + __expf(-lt)) + 0.01f;
  const float C = marg;
  const float d_tot = accums[0] * LN2F;
  const float d_diag = accums[1] * LN2F;
  const float bf = (float)BN;
  const float mean_lse = accums[2] / bf + C;
  const float sum_scores = -d_tot / tau + marg * (bf * bf - bf);  // margin closed-form
  const float sum_diag_scores = -d_diag / tau;
  const float loss = mean_lse
                   - (1.f - LSMOOTH) * (sum_diag_scores / bf)
                   - LSMOOTH * (sum_scores / (bf * bf));
  out[0] = loss;
  out[1] = d_diag / bf;   // pos_dist
  out[2] = tau;
  out[3] = mg;            // maximum(margin, margin) == margin
}

extern "C" void kernel_launch(void* const* d_in, const int* in_sizes, int n_in,
                              void* d_out, int out_size, void* d_ws, size_t ws_size,
                              hipStream_t stream) {
  const float* sign = (const float*)d_in[0];
  const float* text = (const float*)d_in[1];
  const float* p_log_tau = (const float*)d_in[2];
  const float* p_margin = (const float*)d_in[3];
  float* out = (float*)d_out;

  char* ws = (char*)d_ws;
  uint8_t* Aq = (uint8_t*)ws;                                        // 8 MiB
  uint8_t* Bq = (uint8_t*)(ws + (size_t)BN * DK);                    // 8 MiB
  float* xx = (float*)(ws + (size_t)BN * DK * 2);
  float* yy = xx + BN;
  float* row_partial = yy + BN;                                      // 32 x 8192 floats
  float* accums = row_partial + 32 * BN;                             // 3 floats

  prep_kernel<<<dim3(2 * BN), 256, 0, stream>>>(sign, text, (uint32_t*)Aq, (uint32_t*)Bq,
                                                xx, yy, accums);
  gemm_fused<<<dim3(BN / 256, BN / 256), 512, 0, stream>>>(
      Aq, Bq, xx, yy, p_log_tau, p_margin, row_partial, accums);
  logsum_kernel<<<dim3(BN / 256), 256, 0, stream>>>(row_partial, accums);
  final_kernel<<<1, 1, 0, stream>>>(accums, p_log_tau, p_margin, out);
}